// Round 20
// baseline (340.235 us; speedup 1.0000x reference)
//
#include <hip/hip_runtime.h>
#include <hip/hip_bf16.h>

#define T_ 2048
#define N_ 1024
#define NCH 8

typedef __bf16 bf16x8 __attribute__((ext_vector_type(8)));
typedef _Float16 f16x4 __attribute__((ext_vector_type(4)));
typedef __fp16 fp16x2 __attribute__((ext_vector_type(2)));
typedef float f32x4 __attribute__((ext_vector_type(4)));

// exp-based gelu (A&S 7.1.25, |erf err| <= 2.5e-5) — transformer side
__device__ __forceinline__ float gelu_f(float x) {
    float a = fabsf(x) * 0.7071067811865476f;
    float t = __builtin_amdgcn_rcpf(fmaf(0.47047f, a, 1.0f));
    float poly = t * fmaf(t, fmaf(t, 0.3739278f, -0.0479399f), 0.1740121f);
    float hq = poly * __expf(-a * a);          // 0.5*erfc(a)
    return fmaf(fabsf(x), 0.5f - hq, 0.5f * x);
}
// rational gelu (A&S 7.1.27, |erf err| <= 5e-4), no exp — pair kernel
__device__ __forceinline__ float gelu_r(float x) {
    float a = fabsf(x) * 0.7071067811865476f;
    float p = fmaf(a, fmaf(a, fmaf(a, fmaf(a, 0.078108f, 0.000972f), 0.230389f), 0.278393f), 1.0f);
    float p2 = p * p;
    float r = __builtin_amdgcn_rcpf(p2 * p2);   // ~ erfc(a)
    return fmaf(fabsf(x), fmaf(-0.5f, r, 0.5f), 0.5f * x);
}

// ---------------- fused prologue: qe+q1 (512 blocks) | kv 5-slab (1280) | prep (1) ----------------
__global__ void pre_kernel(const float* __restrict__ qpts, const float* __restrict__ qW1,
                           const float* __restrict__ qb1, const float* __restrict__ qW2,
                           const float* __restrict__ qb2, const float* __restrict__ aw,
                           const float* __restrict__ pw1, const float* __restrict__ H,
                           const float* __restrict__ pm_W2, const float* __restrict__ g,
                           const float* __restrict__ bln, const float* __restrict__ b2,
                           float* __restrict__ z, float* __restrict__ q,
                           float* __restrict__ kb1, float* __restrict__ vb1,
                           float* __restrict__ kb2, float* __restrict__ vb2,
                           float* __restrict__ aH, __bf16* __restrict__ w2g,
                           float* __restrict__ kgv, float* __restrict__ kbv) {
    int b = blockIdx.x;
    int w = threadIdx.x >> 6, l = threadIdx.x & 63;
    if (b < 512) {
        int t = b * 4 + w;
        __shared__ float inp[4][52];
        __shared__ float h[4][64];
        __shared__ float zs[4][64];
        float q0 = qpts[t*3+0], q1v = qpts[t*3+1], q2v = qpts[t*3+2];
        if (l < 3) inp[w][l] = (l==0?q0:(l==1?q1v:q2v));
        if (l < 48) {
            int i = l >> 4, r = l & 15, f = r & 7;
            float qv = (i==0?q0:(i==1?q1v:q2v));
            float ang = qv * ((float)(1<<f) * 3.14159265358979323846f);
            inp[w][3+l] = (r < 8) ? __sinf(ang) : __cosf(ang);
        }
        __builtin_amdgcn_wave_barrier();
        float s = qb1[l];
        #pragma unroll
        for (int j = 0; j < 51; ++j) s += inp[w][j] * qW1[l*51+j];
        h[w][l] = gelu_f(s);
        __builtin_amdgcn_wave_barrier();
        float s2 = qb2[l];
        #pragma unroll
        for (int k = 0; k < 64; k += 4) {
            f32x4 wv = *(const f32x4*)&qW2[l*64+k];
            s2 += h[w][k]*wv[0] + h[w][k+1]*wv[1] + h[w][k+2]*wv[2] + h[w][k+3]*wv[3];
        }
        zs[w][l] = s2;
        z[t*64+l] = s2;
        __builtin_amdgcn_wave_barrier();
        float qs = 0.f;
        #pragma unroll
        for (int k = 0; k < 64; k += 4) {
            f32x4 wv = *(const f32x4*)&aw[l*64+k];
            qs += zs[w][k]*wv[0] + zs[w][k+1]*wv[1] + zs[w][k+2]*wv[2] + zs[w][k+3]*wv[3];
        }
        q[t*64+l] = qs;
    } else if (b < 512 + 1280) {
        int bb = b - 512;
        int s = bb % 5;          // 0:k1 1:v1 2:k2 3:v2 4:aH
        int gidx = bb / 5;       // 0..255
        int n = gidx * 4 + w;
        __shared__ float r[4][64];
        r[w][l] = H[n*64+l];
        __builtin_amdgcn_wave_barrier();
        const float* wrow =
            (s == 0) ? (aw + (64+l)*64) :
            (s == 1) ? (aw + (128+l)*64) :
            (s == 2) ? (aw + 192*64 + (64+l)*64) :
            (s == 3) ? (aw + 192*64 + (128+l)*64) :
                       (pw1 + l*128 + 64);
        float* dst =
            (s == 0) ? kb1 : (s == 1) ? vb1 : (s == 2) ? kb2 : (s == 3) ? vb2 : aH;
        float acc = 0.f;
        #pragma unroll
        for (int k = 0; k < 64; k += 4) {
            f32x4 wv = *(const f32x4*)&wrow[k];
            acc += r[w][k]*wv[0] + r[w][k+1]*wv[1] + r[w][k+2]*wv[2] + r[w][k+3]*wv[3];
        }
        dst[n*64+l] = acc;
    } else {
        if (threadIdx.x < 64) {
            int c = threadIdx.x;
            float sg = 0.f, sb = 0.f;
            #pragma unroll
            for (int d = 0; d < 64; ++d) {
                float wv = pm_W2[c*64 + d];
                float gg = g[d];
                w2g[c*64 + d] = (__bf16)(wv * gg);
                sg = fmaf(wv, gg, sg);
                sb = fmaf(wv, bln[d], sb);
            }
            kgv[c] = sg;
            kbv[c] = sb + b2[c];
        }
    }
}

// ---------------- attention partials (layer 0 only): NCH=8 ----------------
__global__ void attn_part_kernel(const float* __restrict__ q, const float* __restrict__ kb,
                                 const float* __restrict__ vb,
                                 float* __restrict__ ps, float* __restrict__ pa) {
    int w = threadIdx.x >> 6, lane = threadIdx.x & 63;
    int bid = blockIdx.x;                 // (h*8 + c)*32 + tg
    int tg = bid & 31;
    int c  = (bid >> 5) & 7;
    int h  = bid >> 8;
    int t = tg*64 + lane;
    __shared__ float red[4][64][17];
    float qv[16];
    #pragma unroll
    for (int d = 0; d < 16; ++d) qv[d] = q[t*64 + h*16 + d];
    float ssum = 0.f;
    float acc[16];
    #pragma unroll
    for (int d = 0; d < 16; ++d) acc[d] = 0.f;
    for (int i = 0; i < 32; ++i) {
        int n = c*128 + w*32 + i;
        const float* kr = kb + n*64 + h*16;
        const float* vr = vb + n*64 + h*16;
        float s = 0.f;
        #pragma unroll
        for (int d = 0; d < 16; ++d) s += qv[d] * kr[d];
        float wt = __expf(s * 0.25f);
        ssum += wt;
        #pragma unroll
        for (int d = 0; d < 16; ++d) acc[d] += wt * vr[d];
    }
    #pragma unroll
    for (int d = 0; d < 16; ++d) red[w][lane][d] = acc[d];
    red[w][lane][16] = ssum;
    __syncthreads();
    int tt = threadIdx.x & 63, dq = threadIdx.x >> 6;
    float r0=0.f, r1=0.f, r2=0.f, r3=0.f, sv=0.f;
    #pragma unroll
    for (int ww = 0; ww < 4; ++ww) {
        r0 += red[ww][tt][dq*4+0];
        r1 += red[ww][tt][dq*4+1];
        r2 += red[ww][tt][dq*4+2];
        r3 += red[ww][tt][dq*4+3];
        sv += red[ww][tt][16];
    }
    int idx = (h*NCH + c)*T_ + tg*64 + tt;
    f32x4 vvv = {r0, r1, r2, r3};
    *(f32x4*)&pa[idx*16 + dq*4] = vvv;
    if (dq == 3) ps[idx] = sv;
}

// ---------------- head (layer 0 only): combine + out-proj + LN + FFN + LN + q2 ----------------
__global__ void __launch_bounds__(256) head_kernel(
        const float* __restrict__ ps, const float* __restrict__ pa,
        const float* __restrict__ Wout, const float* __restrict__ ln1g,
        const float* __restrict__ ln1b, const float* __restrict__ fW1,
        const float* __restrict__ fb1, const float* __restrict__ fW2,
        const float* __restrict__ fb2, const float* __restrict__ ln2g,
        const float* __restrict__ ln2b, const float* __restrict__ nextW,
        int nextStride, float* __restrict__ z, float* __restrict__ qout) {
    int w = threadIdx.x >> 6, l = threadIdx.x & 63;
    int t = blockIdx.x * 4 + w;
    __shared__ float osh[4][64], xr[4][64], zsh[4][64];
    __shared__ __align__(16) float hsh[4][256];
    int h = l >> 4, d = l & 15;
    float at = 0.f, st = 0.f;
    #pragma unroll
    for (int c = 0; c < NCH; ++c) {
        int idx = (h*NCH + c)*T_ + t;
        st += ps[idx];
        at += pa[idx*16 + d];
    }
    osh[w][l] = at / st;
    __builtin_amdgcn_wave_barrier();
    float s = z[t*64+l];
    #pragma unroll
    for (int k = 0; k < 64; k += 4) {
        f32x4 wv = *(const f32x4*)&Wout[l*64+k];
        s += osh[w][k]*wv[0] + osh[w][k+1]*wv[1] + osh[w][k+2]*wv[2] + osh[w][k+3]*wv[3];
    }
    float s1 = s, s2 = s*s;
    #pragma unroll
    for (int m = 32; m >= 1; m >>= 1) { s1 += __shfl_xor(s1, m); s2 += __shfl_xor(s2, m); }
    float mean = s1 * (1.f/64.f);
    float var = s2 * (1.f/64.f) - mean*mean;
    float xv = (s - mean) * rsqrtf(var + 1e-5f) * ln1g[l] + ln1b[l];
    xr[w][l] = xv;
    __builtin_amdgcn_wave_barrier();
    f32x4 hv;
    #pragma unroll
    for (int r = 0; r < 4; ++r) {
        int j = 4*l + r;
        float ss = fb1[j];
        #pragma unroll
        for (int k = 0; k < 64; k += 4) {
            f32x4 wv = *(const f32x4*)&fW1[j*64+k];
            ss += xr[w][k]*wv[0] + xr[w][k+1]*wv[1] + xr[w][k+2]*wv[2] + xr[w][k+3]*wv[3];
        }
        hv[r] = gelu_f(ss);
    }
    *(f32x4*)&hsh[w][4*l] = hv;
    __builtin_amdgcn_wave_barrier();
    float v = fb2[l];
    #pragma unroll
    for (int k = 0; k < 256; k += 4) {
        f32x4 wv = *(const f32x4*)&fW2[l*256+k];
        v += hsh[w][k]*wv[0] + hsh[w][k+1]*wv[1] + hsh[w][k+2]*wv[2] + hsh[w][k+3]*wv[3];
    }
    v += xv;
    s1 = v; s2 = v*v;
    #pragma unroll
    for (int m = 32; m >= 1; m >>= 1) { s1 += __shfl_xor(s1, m); s2 += __shfl_xor(s2, m); }
    mean = s1 * (1.f/64.f);
    var = s2 * (1.f/64.f) - mean*mean;
    float zo = (v - mean) * rsqrtf(var + 1e-5f) * ln2g[l] + ln2b[l];
    zsh[w][l] = zo;
    z[t*64+l] = zo;
    __builtin_amdgcn_wave_barrier();
    float qv = 0.f;
    #pragma unroll
    for (int k = 0; k < 64; k += 4) {
        f32x4 wv = *(const f32x4*)&nextW[l*nextStride+k];
        qv += zsh[w][k]*wv[0] + zsh[w][k+1]*wv[1] + zsh[w][k+2]*wv[2] + zsh[w][k+3]*wv[3];
    }
    qout[t*64+l] = qv;
}

// ---------------- pair kernel with fused attn(layer1) + head(layer1) prologue ----------------
// block = one t. Prologue: (a) attention for this t — wave w = head w, lane handles 16 n
// (stride 64), butterfly reduce, lane0 writes osh; (b) out-proj -> LN -> FFN -> LN -> az(+b1).
// Then 16-tile pair loop (v7). launch_bounds stays (256,3): (256,4) = 64-VGPR spill cliff
// (r9/r10/r18 evidence).
__global__ void __launch_bounds__(256, 3) pair_kernel(
        const float* __restrict__ q2, const float* __restrict__ kb2,
        const float* __restrict__ vb2,
        const float* __restrict__ Wout, const float* __restrict__ ln1g,
        const float* __restrict__ ln1b, const float* __restrict__ fW1,
        const float* __restrict__ fb1, const float* __restrict__ fW2,
        const float* __restrict__ fb2, const float* __restrict__ ln2g,
        const float* __restrict__ ln2b, const float* __restrict__ pw1,
        const float* __restrict__ z, const float* __restrict__ b1,
        const float* __restrict__ aH, const __bf16* __restrict__ w2g,
        const float* __restrict__ kgv, const float* __restrict__ kbv,
        const float* __restrict__ W3, const float* __restrict__ b3,
        float* __restrict__ out) {
    int w = threadIdx.x >> 6, lane = threadIdx.x & 63;
    int t = blockIdx.x, qd = w;
    int cLo = lane & 15, kg = lane >> 4;

    __shared__ __align__(16) char w2s[8192];
    __shared__ __align__(16) float kk[128];
    __shared__ float osh[64], xrs[64], azs[64];
    __shared__ __align__(16) float hshp[256];

    // stage W2g (bf16, XOR-swizzled) + Kg/Kb into LDS
    {
        int i = threadIdx.x;
        #pragma unroll
        for (int hh = 0; hh < 2; ++hh) {
            int elem = i * 16 + hh * 8;
            int row = elem >> 6;
            int colb = (elem & 63) << 1;
            int sw = colb ^ ((row & 7) << 4);
            *(uint4*)(w2s + row * 128 + sw) = *(const uint4*)((const char*)w2g + elem * 2);
        }
        if (i < 64) kk[i] = kgv[i];
        else if (i < 128) kk[i] = kbv[i - 64];
    }

    // ---- attention (layer 1) for this t: wave w = head w ----
    {
        float qv[16];
        #pragma unroll
        for (int d = 0; d < 16; d += 4) {
            f32x4 v4 = *(const f32x4*)&q2[t*64 + w*16 + d];
            qv[d] = v4[0]; qv[d+1] = v4[1]; qv[d+2] = v4[2]; qv[d+3] = v4[3];
        }
        float acc[16];
        #pragma unroll
        for (int d = 0; d < 16; ++d) acc[d] = 0.f;
        float ssum = 0.f;
        #pragma unroll 1
        for (int i = 0; i < 16; ++i) {
            int n = i*64 + lane;
            const float* kr = kb2 + n*64 + w*16;
            const float* vr = vb2 + n*64 + w*16;
            float s = 0.f;
            #pragma unroll
            for (int d = 0; d < 16; d += 4) {
                f32x4 k4 = *(const f32x4*)&kr[d];
                s += qv[d]*k4[0] + qv[d+1]*k4[1] + qv[d+2]*k4[2] + qv[d+3]*k4[3];
            }
            float wt = __expf(s * 0.25f);
            ssum += wt;
            #pragma unroll
            for (int d = 0; d < 16; d += 4) {
                f32x4 v4 = *(const f32x4*)&vr[d];
                acc[d]   = fmaf(wt, v4[0], acc[d]);
                acc[d+1] = fmaf(wt, v4[1], acc[d+1]);
                acc[d+2] = fmaf(wt, v4[2], acc[d+2]);
                acc[d+3] = fmaf(wt, v4[3], acc[d+3]);
            }
        }
        // butterfly reduce across 64 lanes (17 values)
        #pragma unroll
        for (int m = 1; m < 64; m <<= 1) {
            ssum += __shfl_xor(ssum, m);
            #pragma unroll
            for (int d = 0; d < 16; ++d) acc[d] += __shfl_xor(acc[d], m);
        }
        if (lane == 0) {
            float inv = 1.0f / ssum;
            #pragma unroll
            for (int d = 0; d < 16; ++d) osh[w*16 + d] = acc[d] * inv;
        }
        __syncthreads();
    }

    // ---- head(layer1) rest of prologue for this t ----
    {
        int j = threadIdx.x;
        if (j < 64) {
            float s = z[t*64+j];
            #pragma unroll
            for (int k = 0; k < 64; k += 4) {
                f32x4 wv = *(const f32x4*)&Wout[j*64+k];
                s += osh[k]*wv[0] + osh[k+1]*wv[1] + osh[k+2]*wv[2] + osh[k+3]*wv[3];
            }
            float s1 = s, s2 = s*s;
            #pragma unroll
            for (int m = 32; m >= 1; m >>= 1) { s1 += __shfl_xor(s1, m); s2 += __shfl_xor(s2, m); }
            float mean = s1 * (1.f/64.f);
            float var = s2 * (1.f/64.f) - mean*mean;
            xrs[j] = (s - mean) * rsqrtf(var + 1e-5f) * ln1g[j] + ln1b[j];
        }
        __syncthreads();
        {
            float ss = fb1[j];
            #pragma unroll
            for (int k = 0; k < 64; k += 4) {
                f32x4 wv = *(const f32x4*)&fW1[j*64+k];
                ss += xrs[k]*wv[0] + xrs[k+1]*wv[1] + xrs[k+2]*wv[2] + xrs[k+3]*wv[3];
            }
            hshp[j] = gelu_f(ss);
        }
        __syncthreads();
        if (j < 64) {
            float v = fb2[j];
            #pragma unroll
            for (int k = 0; k < 256; k += 4) {
                f32x4 wv = *(const f32x4*)&fW2[j*256+k];
                v += hshp[k]*wv[0] + hshp[k+1]*wv[1] + hshp[k+2]*wv[2] + hshp[k+3]*wv[3];
            }
            v += xrs[j];
            float s1 = v, s2 = v*v;
            #pragma unroll
            for (int m = 32; m >= 1; m >>= 1) { s1 += __shfl_xor(s1, m); s2 += __shfl_xor(s2, m); }
            float mean = s1 * (1.f/64.f);
            float var = s2 * (1.f/64.f) - mean*mean;
            osh[j] = (v - mean) * rsqrtf(var + 1e-5f) * ln2g[j] + ln2b[j];   // zsh reuse
        }
        __syncthreads();
        if (j < 64) {
            float av = b1[j];
            #pragma unroll
            for (int k = 0; k < 64; k += 4) {
                f32x4 wv = *(const f32x4*)&pw1[j*128+k];
                av += osh[k]*wv[0] + osh[k+1]*wv[1] + osh[k+2]*wv[2] + osh[k+3]*wv[3];
            }
            azs[j] = av;   // az + b1 folded
        }
        __syncthreads();
    }

    // ---- pair main loop (v7) ----
    float azc[16];
    #pragma unroll
    for (int kt = 0; kt < 2; ++kt)
        #pragma unroll
        for (int hh = 0; hh < 2; ++hh) {
            f32x4 av = *(const f32x4*)&azs[kt*32 + kg*8 + hh*4];
            #pragma unroll
            for (int j = 0; j < 4; ++j) azc[kt*8 + hh*4 + j] = av[j];
        }
    f16x4 w3f[4];
    #pragma unroll
    for (int ct = 0; ct < 4; ++ct)
        #pragma unroll
        for (int j = 0; j < 4; ++j)
            w3f[ct][j] = (cLo < 3) ? (_Float16)W3[cLo*64 + ct*16 + kg*4 + j] : (_Float16)0.0f;
    float b30 = b3[0], b31 = b3[1], b32v = b3[2];

    const float* aHb = aH + (qd*256 + cLo) * 64 + kg * 8;
    int swz = (cLo & 7) << 4;
    const char* wrow0 = w2s + cLo * 128;

    auto LOADTILE = [&](f32x4* buf, int k) {
        const float* p = aHb + k * 1024;
        buf[0] = *(const f32x4*)(p);
        buf[1] = *(const f32x4*)(p + 4);
        buf[2] = *(const f32x4*)(p + 32);
        buf[3] = *(const f32x4*)(p + 36);
    };

    auto BODY = [&](const f32x4* buf, int tile) {
        bf16x8 uf[2];
        float s1 = 0.f, s2 = 0.f;
        #pragma unroll
        for (int kt = 0; kt < 2; ++kt)
            #pragma unroll
            for (int hh = 0; hh < 2; ++hh) {
                f32x4 vv = buf[kt*2+hh];
                #pragma unroll
                for (int j = 0; j < 4; ++j) {
                    float uu = gelu_r(azc[kt*8 + hh*4 + j] + vv[j]);
                    uf[kt][hh*4+j] = (__bf16)uu;
                    s1 += uu; s2 = fmaf(uu, uu, s2);
                }
            }
        float a16 = __shfl_xor(s1, 16), a32 = __shfl_xor(s1, 32), a48 = __shfl_xor(s1, 48);
        float c16 = __shfl_xor(s2, 16), c32 = __shfl_xor(s2, 32), c48 = __shfl_xor(s2, 48);
        float t1 = (s1 + a16) + (a32 + a48);
        float t2 = (s2 + c16) + (c32 + c48);
        float mean = t1 * 0.015625f;
        float var  = fmaf(t2, 0.015625f, -mean * mean);
        float inv  = rsqrtf(var + 1e-5f);
        float im   = inv * mean;

        f32x4 acc[4];
        #pragma unroll
        for (int ct = 0; ct < 4; ++ct) acc[ct] = (f32x4){0.f, 0.f, 0.f, 0.f};
        #pragma unroll
        for (int ct = 0; ct < 4; ++ct) {
            const char* wr = wrow0 + ct * 2048;
            #pragma unroll
            for (int kt = 0; kt < 2; ++kt) {
                bf16x8 wfr = *(const bf16x8*)(wr + ((kt*64 + kg*16) ^ swz));
                acc[ct] = __builtin_amdgcn_mfma_f32_16x16x32_bf16(wfr, uf[kt], acc[ct], 0, 0, 0);
            }
        }
        f32x4 acc2 = (f32x4){0.f, 0.f, 0.f, 0.f};
        #pragma unroll
        for (int ct = 0; ct < 4; ++ct) {
            f32x4 g4 = *(const f32x4*)&kk[ct*16 + kg*4];
            f32x4 b4 = *(const f32x4*)&kk[64 + ct*16 + kg*4];
            float v0 = gelu_r(fmaf(inv, acc[ct][0], fmaf(-im, g4[0], b4[0])));
            float v1 = gelu_r(fmaf(inv, acc[ct][1], fmaf(-im, g4[1], b4[1])));
            float v2 = gelu_r(fmaf(inv, acc[ct][2], fmaf(-im, g4[2], b4[2])));
            float v3 = gelu_r(fmaf(inv, acc[ct][3], fmaf(-im, g4[3], b4[3])));
            fp16x2 lo = __builtin_amdgcn_cvt_pkrtz(v0, v1);
            fp16x2 hi = __builtin_amdgcn_cvt_pkrtz(v2, v3);
            f16x4 vgf;
            vgf[0] = (_Float16)lo[0]; vgf[1] = (_Float16)lo[1];
            vgf[2] = (_Float16)hi[0]; vgf[3] = (_Float16)hi[1];
            acc2 = __builtin_amdgcn_mfma_f32_16x16x16f16(w3f[ct], vgf, acc2, 0, 0, 0);
        }
        if (kg == 0) {
            float* op = out + t*3072 + (tile*16 + cLo)*3;
            op[0] = acc2[0] + b30;
            op[1] = acc2[1] + b31;
            op[2] = acc2[2] + b32v;
        }
    };

    f32x4 bufA[4], bufB[4];
    LOADTILE(bufA, 0);
    #pragma unroll 1
    for (int k = 0; k < 16; k += 2) {
        LOADTILE(bufB, k + 1);
        BODY(bufA, qd*16 + k);
        if (k + 2 < 16) LOADTILE(bufA, k + 2);
        BODY(bufB, qd*16 + k + 1);
    }
}

extern "C" void kernel_launch(void* const* d_in, const int* in_sizes, int n_in,
                              void* d_out, int out_size, void* d_ws, size_t ws_size,
                              hipStream_t stream) {
    const float* H         = (const float*)d_in[0];
    const float* qpts      = (const float*)d_in[1];
    const float* qe_W1     = (const float*)d_in[2];
    const float* qe_b1     = (const float*)d_in[3];
    const float* qe_W2     = (const float*)d_in[4];
    const float* qe_b2     = (const float*)d_in[5];
    const float* attn_in_w = (const float*)d_in[6];
    const float* attn_out_w= (const float*)d_in[7];
    const float* ln1_g     = (const float*)d_in[8];
    const float* ln1_b     = (const float*)d_in[9];
    const float* ffn_W1    = (const float*)d_in[10];
    const float* ffn_b1    = (const float*)d_in[11];
    const float* ffn_W2    = (const float*)d_in[12];
    const float* ffn_b2    = (const float*)d_in[13];
    const float* ln2_g     = (const float*)d_in[14];
    const float* ln2_b     = (const float*)d_in[15];
    const float* pm_W1     = (const float*)d_in[16];
    const float* pm_b1     = (const float*)d_in[17];
    const float* pm_ln_g   = (const float*)d_in[18];
    const float* pm_ln_b   = (const float*)d_in[19];
    const float* pm_W2     = (const float*)d_in[20];
    const float* pm_b2     = (const float*)d_in[21];
    const float* pm_W3     = (const float*)d_in[22];
    const float* pm_b3     = (const float*)d_in[23];

    float* ws = (float*)d_ws;
    float* z   = ws;             // 131072
    float* q   = ws + 131072;    // 131072 (q1, then q2)
    float* kb1 = ws + 262144;    // 65536
    float* vb1 = ws + 327680;    // 65536
    float* kb2 = ws + 393216;    // 65536
    float* vb2 = ws + 458752;    // 65536
    float* aH  = ws + 524288;    // 65536
    float* ps  = ws + 720896;    // 65536 (NCH=8)
    float* pa  = ws + 851968;    // 1048576
    __bf16* w2g = (__bf16*)(ws + 2949120);   // 4096 bf16
    float* kgv = ws + 2951168;   // 64
    float* kbv = ws + 2951232;   // 64
    float* out = (float*)d_out;

    pre_kernel<<<512 + 1280 + 1, 256, 0, stream>>>(
        qpts, qe_W1, qe_b1, qe_W2, qe_b2, attn_in_w, pm_W1, H,
        pm_W2, pm_ln_g, pm_ln_b, pm_b2,
        z, q, kb1, vb1, kb2, vb2, aH, w2g, kgv, kbv);
    // layer 0
    attn_part_kernel<<<1024, 256, 0, stream>>>(q, kb1, vb1, ps, pa);
    head_kernel<<<T_/4, 256, 0, stream>>>(ps, pa, attn_out_w, ln1_g, ln1_b,
                                          ffn_W1, ffn_b1, ffn_W2, ffn_b2, ln2_g, ln2_b,
                                          attn_in_w + 192*64, 64, z, q);
    // layer 1 attention + head fused into pair prologue
    pair_kernel<<<2048, 256, 0, stream>>>(
        q, kb2, vb2, attn_out_w + 64*64, ln1_g + 64, ln1_b + 64,
        ffn_W1 + 256*64, ffn_b1 + 256, ffn_W2 + 64*256, ffn_b2 + 64,
        ln2_g + 64, ln2_b + 64, pm_W1, z, pm_b1,
        aH, w2g, kgv, kbv, pm_W3, pm_b3, out);
}

// Round 21
// 276.722 us; speedup vs baseline: 1.2295x; 1.2295x over previous
//
#include <hip/hip_runtime.h>
#include <hip/hip_bf16.h>

#define T_ 2048
#define N_ 1024
#define NCH 8

typedef __bf16 bf16x8 __attribute__((ext_vector_type(8)));
typedef _Float16 f16x4 __attribute__((ext_vector_type(4)));
typedef __fp16 fp16x2 __attribute__((ext_vector_type(2)));
typedef float f32x4 __attribute__((ext_vector_type(4)));

// exp-based gelu (A&S 7.1.25, |erf err| <= 2.5e-5) — transformer side
__device__ __forceinline__ float gelu_f(float x) {
    float a = fabsf(x) * 0.7071067811865476f;
    float t = __builtin_amdgcn_rcpf(fmaf(0.47047f, a, 1.0f));
    float poly = t * fmaf(t, fmaf(t, 0.3739278f, -0.0479399f), 0.1740121f);
    float hq = poly * __expf(-a * a);          // 0.5*erfc(a)
    return fmaf(fabsf(x), 0.5f - hq, 0.5f * x);
}
// rational gelu (A&S 7.1.27, |erf err| <= 5e-4), no exp — pair kernel
__device__ __forceinline__ float gelu_r(float x) {
    float a = fabsf(x) * 0.7071067811865476f;
    float p = fmaf(a, fmaf(a, fmaf(a, fmaf(a, 0.078108f, 0.000972f), 0.230389f), 0.278393f), 1.0f);
    float p2 = p * p;
    float r = __builtin_amdgcn_rcpf(p2 * p2);   // ~ erfc(a)
    return fmaf(fabsf(x), fmaf(-0.5f, r, 0.5f), 0.5f * x);
}

// ---------------- fused prologue: qe+q1 (512 blocks) | kv 5-slab (1280) | prep (1) ----------------
__global__ void pre_kernel(const float* __restrict__ qpts, const float* __restrict__ qW1,
                           const float* __restrict__ qb1, const float* __restrict__ qW2,
                           const float* __restrict__ qb2, const float* __restrict__ aw,
                           const float* __restrict__ pw1, const float* __restrict__ H,
                           const float* __restrict__ pm_W2, const float* __restrict__ g,
                           const float* __restrict__ bln, const float* __restrict__ b2,
                           float* __restrict__ z, float* __restrict__ q,
                           float* __restrict__ kb1, float* __restrict__ vb1,
                           float* __restrict__ kb2, float* __restrict__ vb2,
                           float* __restrict__ aH, __bf16* __restrict__ w2g,
                           float* __restrict__ kgv, float* __restrict__ kbv) {
    int b = blockIdx.x;
    int w = threadIdx.x >> 6, l = threadIdx.x & 63;
    if (b < 512) {
        int t = b * 4 + w;
        __shared__ float inp[4][52];
        __shared__ float h[4][64];
        __shared__ float zs[4][64];
        float q0 = qpts[t*3+0], q1v = qpts[t*3+1], q2v = qpts[t*3+2];
        if (l < 3) inp[w][l] = (l==0?q0:(l==1?q1v:q2v));
        if (l < 48) {
            int i = l >> 4, r = l & 15, f = r & 7;
            float qv = (i==0?q0:(i==1?q1v:q2v));
            float ang = qv * ((float)(1<<f) * 3.14159265358979323846f);
            inp[w][3+l] = (r < 8) ? __sinf(ang) : __cosf(ang);
        }
        __builtin_amdgcn_wave_barrier();
        float s = qb1[l];
        #pragma unroll
        for (int j = 0; j < 51; ++j) s += inp[w][j] * qW1[l*51+j];
        h[w][l] = gelu_f(s);
        __builtin_amdgcn_wave_barrier();
        float s2 = qb2[l];
        #pragma unroll
        for (int k = 0; k < 64; k += 4) {
            f32x4 wv = *(const f32x4*)&qW2[l*64+k];
            s2 += h[w][k]*wv[0] + h[w][k+1]*wv[1] + h[w][k+2]*wv[2] + h[w][k+3]*wv[3];
        }
        zs[w][l] = s2;
        z[t*64+l] = s2;
        __builtin_amdgcn_wave_barrier();
        float qs = 0.f;
        #pragma unroll
        for (int k = 0; k < 64; k += 4) {
            f32x4 wv = *(const f32x4*)&aw[l*64+k];
            qs += zs[w][k]*wv[0] + zs[w][k+1]*wv[1] + zs[w][k+2]*wv[2] + zs[w][k+3]*wv[3];
        }
        q[t*64+l] = qs;
    } else if (b < 512 + 1280) {
        int bb = b - 512;
        int s = bb % 5;          // 0:k1 1:v1 2:k2 3:v2 4:aH
        int gidx = bb / 5;       // 0..255
        int n = gidx * 4 + w;
        __shared__ float r[4][64];
        r[w][l] = H[n*64+l];
        __builtin_amdgcn_wave_barrier();
        const float* wrow =
            (s == 0) ? (aw + (64+l)*64) :
            (s == 1) ? (aw + (128+l)*64) :
            (s == 2) ? (aw + 192*64 + (64+l)*64) :
            (s == 3) ? (aw + 192*64 + (128+l)*64) :
                       (pw1 + l*128 + 64);
        float* dst =
            (s == 0) ? kb1 : (s == 1) ? vb1 : (s == 2) ? kb2 : (s == 3) ? vb2 : aH;
        float acc = 0.f;
        #pragma unroll
        for (int k = 0; k < 64; k += 4) {
            f32x4 wv = *(const f32x4*)&wrow[k];
            acc += r[w][k]*wv[0] + r[w][k+1]*wv[1] + r[w][k+2]*wv[2] + r[w][k+3]*wv[3];
        }
        dst[n*64+l] = acc;
    } else {
        if (threadIdx.x < 64) {
            int c = threadIdx.x;
            float sg = 0.f, sb = 0.f;
            #pragma unroll
            for (int d = 0; d < 64; ++d) {
                float wv = pm_W2[c*64 + d];
                float gg = g[d];
                w2g[c*64 + d] = (__bf16)(wv * gg);
                sg = fmaf(wv, gg, sg);
                sb = fmaf(wv, bln[d], sb);
            }
            kgv[c] = sg;
            kbv[c] = sb + b2[c];
        }
    }
}

// ---------------- attention partials: NCH=8, block = (h, chunk, t-group), 4 waves split n ----------------
__global__ void attn_part_kernel(const float* __restrict__ q, const float* __restrict__ kb,
                                 const float* __restrict__ vb,
                                 float* __restrict__ ps, float* __restrict__ pa) {
    int w = threadIdx.x >> 6, lane = threadIdx.x & 63;
    int bid = blockIdx.x;                 // (h*8 + c)*32 + tg
    int tg = bid & 31;
    int c  = (bid >> 5) & 7;
    int h  = bid >> 8;
    int t = tg*64 + lane;
    __shared__ float red[4][64][17];
    float qv[16];
    #pragma unroll
    for (int d = 0; d < 16; ++d) qv[d] = q[t*64 + h*16 + d];
    float ssum = 0.f;
    float acc[16];
    #pragma unroll
    for (int d = 0; d < 16; ++d) acc[d] = 0.f;
    for (int i = 0; i < 32; ++i) {
        int n = c*128 + w*32 + i;
        const float* kr = kb + n*64 + h*16;
        const float* vr = vb + n*64 + h*16;
        float s = 0.f;
        #pragma unroll
        for (int d = 0; d < 16; ++d) s += qv[d] * kr[d];
        float wt = __expf(s * 0.25f);
        ssum += wt;
        #pragma unroll
        for (int d = 0; d < 16; ++d) acc[d] += wt * vr[d];
    }
    #pragma unroll
    for (int d = 0; d < 16; ++d) red[w][lane][d] = acc[d];
    red[w][lane][16] = ssum;
    __syncthreads();
    int tt = threadIdx.x & 63, dq = threadIdx.x >> 6;
    float r0=0.f, r1=0.f, r2=0.f, r3=0.f, sv=0.f;
    #pragma unroll
    for (int ww = 0; ww < 4; ++ww) {
        r0 += red[ww][tt][dq*4+0];
        r1 += red[ww][tt][dq*4+1];
        r2 += red[ww][tt][dq*4+2];
        r3 += red[ww][tt][dq*4+3];
        sv += red[ww][tt][16];
    }
    int idx = (h*NCH + c)*T_ + tg*64 + tt;
    f32x4 vvv = {r0, r1, r2, r3};
    *(f32x4*)&pa[idx*16 + dq*4] = vvv;
    if (dq == 3) ps[idx] = sv;
}

// ---------------- head (layer 0 only): combine + out-proj + LN + FFN + LN + q2 ----------------
__global__ void __launch_bounds__(256) head_kernel(
        const float* __restrict__ ps, const float* __restrict__ pa,
        const float* __restrict__ Wout, const float* __restrict__ ln1g,
        const float* __restrict__ ln1b, const float* __restrict__ fW1,
        const float* __restrict__ fb1, const float* __restrict__ fW2,
        const float* __restrict__ fb2, const float* __restrict__ ln2g,
        const float* __restrict__ ln2b, const float* __restrict__ nextW,
        int nextStride, float* __restrict__ z, float* __restrict__ qout) {
    int w = threadIdx.x >> 6, l = threadIdx.x & 63;
    int t = blockIdx.x * 4 + w;
    __shared__ float osh[4][64], xr[4][64], zsh[4][64];
    __shared__ __align__(16) float hsh[4][256];
    int h = l >> 4, d = l & 15;
    float at = 0.f, st = 0.f;
    #pragma unroll
    for (int c = 0; c < NCH; ++c) {
        int idx = (h*NCH + c)*T_ + t;
        st += ps[idx];
        at += pa[idx*16 + d];
    }
    osh[w][l] = at / st;
    __builtin_amdgcn_wave_barrier();
    float s = z[t*64+l];
    #pragma unroll
    for (int k = 0; k < 64; k += 4) {
        f32x4 wv = *(const f32x4*)&Wout[l*64+k];
        s += osh[w][k]*wv[0] + osh[w][k+1]*wv[1] + osh[w][k+2]*wv[2] + osh[w][k+3]*wv[3];
    }
    float s1 = s, s2 = s*s;
    #pragma unroll
    for (int m = 32; m >= 1; m >>= 1) { s1 += __shfl_xor(s1, m); s2 += __shfl_xor(s2, m); }
    float mean = s1 * (1.f/64.f);
    float var = s2 * (1.f/64.f) - mean*mean;
    float xv = (s - mean) * rsqrtf(var + 1e-5f) * ln1g[l] + ln1b[l];
    xr[w][l] = xv;
    __builtin_amdgcn_wave_barrier();
    f32x4 hv;
    #pragma unroll
    for (int r = 0; r < 4; ++r) {
        int j = 4*l + r;
        float ss = fb1[j];
        #pragma unroll
        for (int k = 0; k < 64; k += 4) {
            f32x4 wv = *(const f32x4*)&fW1[j*64+k];
            ss += xr[w][k]*wv[0] + xr[w][k+1]*wv[1] + xr[w][k+2]*wv[2] + xr[w][k+3]*wv[3];
        }
        hv[r] = gelu_f(ss);
    }
    *(f32x4*)&hsh[w][4*l] = hv;
    __builtin_amdgcn_wave_barrier();
    float v = fb2[l];
    #pragma unroll
    for (int k = 0; k < 256; k += 4) {
        f32x4 wv = *(const f32x4*)&fW2[l*256+k];
        v += hsh[w][k]*wv[0] + hsh[w][k+1]*wv[1] + hsh[w][k+2]*wv[2] + hsh[w][k+3]*wv[3];
    }
    v += xv;
    s1 = v; s2 = v*v;
    #pragma unroll
    for (int m = 32; m >= 1; m >>= 1) { s1 += __shfl_xor(s1, m); s2 += __shfl_xor(s2, m); }
    mean = s1 * (1.f/64.f);
    var = s2 * (1.f/64.f) - mean*mean;
    float zo = (v - mean) * rsqrtf(var + 1e-5f) * ln2g[l] + ln2b[l];
    zsh[w][l] = zo;
    z[t*64+l] = zo;
    __builtin_amdgcn_wave_barrier();
    float qv = 0.f;
    #pragma unroll
    for (int k = 0; k < 64; k += 4) {
        f32x4 wv = *(const f32x4*)&nextW[l*nextStride+k];
        qv += zsh[w][k]*wv[0] + zsh[w][k+1]*wv[1] + zsh[w][k+2]*wv[2] + zsh[w][k+3]*wv[3];
    }
    qout[t*64+l] = qv;
}

// ---------------- pair kernel with fused head (layer 1) prologue ----------------
// block = one t. Prologue (256 thr): combine(ps,pa) -> out-proj -> LN -> FFN -> LN -> az(+b1) in LDS.
// Then 16-tile pair loop (4 waves x n-quarter), v7 structure.
// NOTE: launch_bounds MUST stay (256,3): (256,4) forces the 64-VGPR tier and spills
// (r9/r10/r18 evidence: WRITE_SIZE 77-250MB, 1.3-2x slowdown).
__global__ void __launch_bounds__(256, 3) pair_kernel(
        const float* __restrict__ ps, const float* __restrict__ pa,
        const float* __restrict__ Wout, const float* __restrict__ ln1g,
        const float* __restrict__ ln1b, const float* __restrict__ fW1,
        const float* __restrict__ fb1, const float* __restrict__ fW2,
        const float* __restrict__ fb2, const float* __restrict__ ln2g,
        const float* __restrict__ ln2b, const float* __restrict__ pw1,
        const float* __restrict__ z, const float* __restrict__ b1,
        const float* __restrict__ aH, const __bf16* __restrict__ w2g,
        const float* __restrict__ kgv, const float* __restrict__ kbv,
        const float* __restrict__ W3, const float* __restrict__ b3,
        float* __restrict__ out) {
    int w = threadIdx.x >> 6, lane = threadIdx.x & 63;
    int t = blockIdx.x, qd = w;
    int cLo = lane & 15, kg = lane >> 4;

    __shared__ __align__(16) char w2s[8192];
    __shared__ __align__(16) float kk[128];
    __shared__ float redA[4][64], redS[4][64];
    __shared__ float osh[64], xrs[64], azs[64];
    __shared__ __align__(16) float hshp[256];

    // stage W2g (bf16, XOR-swizzled) + Kg/Kb into LDS
    {
        int i = threadIdx.x;
        #pragma unroll
        for (int hh = 0; hh < 2; ++hh) {
            int elem = i * 16 + hh * 8;
            int row = elem >> 6;
            int colb = (elem & 63) << 1;
            int sw = colb ^ ((row & 7) << 4);
            *(uint4*)(w2s + row * 128 + sw) = *(const uint4*)((const char*)w2g + elem * 2);
        }
        if (i < 64) kk[i] = kgv[i];
        else if (i < 128) kk[i] = kbv[i - 64];
    }

    // ---- head(layer1) prologue for this t ----
    {
        int j = threadIdx.x, dd = j & 63, cq = j >> 6;
        int h = dd >> 4, d = dd & 15;
        float at = 0.f, st = 0.f;
        #pragma unroll
        for (int c = cq*2; c < cq*2+2; ++c) {
            int idx = (h*NCH + c)*T_ + t;
            st += ps[idx];
            at += pa[idx*16 + d];
        }
        redA[cq][dd] = at; redS[cq][dd] = st;
        __syncthreads();
        if (j < 64) {
            float atot = redA[0][j]+redA[1][j]+redA[2][j]+redA[3][j];
            float stot = redS[0][j]+redS[1][j]+redS[2][j]+redS[3][j];
            osh[j] = atot / stot;
        }
        __syncthreads();
        if (j < 64) {
            float s = z[t*64+j];
            #pragma unroll
            for (int k = 0; k < 64; k += 4) {
                f32x4 wv = *(const f32x4*)&Wout[j*64+k];
                s += osh[k]*wv[0] + osh[k+1]*wv[1] + osh[k+2]*wv[2] + osh[k+3]*wv[3];
            }
            float s1 = s, s2 = s*s;
            #pragma unroll
            for (int m = 32; m >= 1; m >>= 1) { s1 += __shfl_xor(s1, m); s2 += __shfl_xor(s2, m); }
            float mean = s1 * (1.f/64.f);
            float var = s2 * (1.f/64.f) - mean*mean;
            xrs[j] = (s - mean) * rsqrtf(var + 1e-5f) * ln1g[j] + ln1b[j];
        }
        __syncthreads();
        {
            float ss = fb1[j];
            #pragma unroll
            for (int k = 0; k < 64; k += 4) {
                f32x4 wv = *(const f32x4*)&fW1[j*64+k];
                ss += xrs[k]*wv[0] + xrs[k+1]*wv[1] + xrs[k+2]*wv[2] + xrs[k+3]*wv[3];
            }
            hshp[j] = gelu_f(ss);
        }
        __syncthreads();
        if (j < 64) {
            float v = fb2[j];
            #pragma unroll
            for (int k = 0; k < 256; k += 4) {
                f32x4 wv = *(const f32x4*)&fW2[j*256+k];
                v += hshp[k]*wv[0] + hshp[k+1]*wv[1] + hshp[k+2]*wv[2] + hshp[k+3]*wv[3];
            }
            v += xrs[j];
            float s1 = v, s2 = v*v;
            #pragma unroll
            for (int m = 32; m >= 1; m >>= 1) { s1 += __shfl_xor(s1, m); s2 += __shfl_xor(s2, m); }
            float mean = s1 * (1.f/64.f);
            float var = s2 * (1.f/64.f) - mean*mean;
            osh[j] = (v - mean) * rsqrtf(var + 1e-5f) * ln2g[j] + ln2b[j];   // zsh reuse
        }
        __syncthreads();
        if (j < 64) {
            float av = b1[j];
            #pragma unroll
            for (int k = 0; k < 64; k += 4) {
                f32x4 wv = *(const f32x4*)&pw1[j*128+k];
                av += osh[k]*wv[0] + osh[k+1]*wv[1] + osh[k+2]*wv[2] + osh[k+3]*wv[3];
            }
            azs[j] = av;   // az + b1 folded
        }
        __syncthreads();
    }

    // ---- pair main loop (v7) ----
    float azc[16];
    #pragma unroll
    for (int kt = 0; kt < 2; ++kt)
        #pragma unroll
        for (int hh = 0; hh < 2; ++hh) {
            f32x4 av = *(const f32x4*)&azs[kt*32 + kg*8 + hh*4];
            #pragma unroll
            for (int j = 0; j < 4; ++j) azc[kt*8 + hh*4 + j] = av[j];
        }
    f16x4 w3f[4];
    #pragma unroll
    for (int ct = 0; ct < 4; ++ct)
        #pragma unroll
        for (int j = 0; j < 4; ++j)
            w3f[ct][j] = (cLo < 3) ? (_Float16)W3[cLo*64 + ct*16 + kg*4 + j] : (_Float16)0.0f;
    float b30 = b3[0], b31 = b3[1], b32v = b3[2];

    const float* aHb = aH + (qd*256 + cLo) * 64 + kg * 8;
    int swz = (cLo & 7) << 4;
    const char* wrow0 = w2s + cLo * 128;

    auto LOADTILE = [&](f32x4* buf, int k) {
        const float* p = aHb + k * 1024;
        buf[0] = *(const f32x4*)(p);
        buf[1] = *(const f32x4*)(p + 4);
        buf[2] = *(const f32x4*)(p + 32);
        buf[3] = *(const f32x4*)(p + 36);
    };

    auto BODY = [&](const f32x4* buf, int tile) {
        bf16x8 uf[2];
        float s1 = 0.f, s2 = 0.f;
        #pragma unroll
        for (int kt = 0; kt < 2; ++kt)
            #pragma unroll
            for (int hh = 0; hh < 2; ++hh) {
                f32x4 vv = buf[kt*2+hh];
                #pragma unroll
                for (int j = 0; j < 4; ++j) {
                    float uu = gelu_r(azc[kt*8 + hh*4 + j] + vv[j]);
                    uf[kt][hh*4+j] = (__bf16)uu;
                    s1 += uu; s2 = fmaf(uu, uu, s2);
                }
            }
        float a16 = __shfl_xor(s1, 16), a32 = __shfl_xor(s1, 32), a48 = __shfl_xor(s1, 48);
        float c16 = __shfl_xor(s2, 16), c32 = __shfl_xor(s2, 32), c48 = __shfl_xor(s2, 48);
        float t1 = (s1 + a16) + (a32 + a48);
        float t2 = (s2 + c16) + (c32 + c48);
        float mean = t1 * 0.015625f;
        float var  = fmaf(t2, 0.015625f, -mean * mean);
        float inv  = rsqrtf(var + 1e-5f);
        float im   = inv * mean;

        f32x4 acc[4];
        #pragma unroll
        for (int ct = 0; ct < 4; ++ct) acc[ct] = (f32x4){0.f, 0.f, 0.f, 0.f};
        #pragma unroll
        for (int ct = 0; ct < 4; ++ct) {
            const char* wr = wrow0 + ct * 2048;
            #pragma unroll
            for (int kt = 0; kt < 2; ++kt) {
                bf16x8 wfr = *(const bf16x8*)(wr + ((kt*64 + kg*16) ^ swz));
                acc[ct] = __builtin_amdgcn_mfma_f32_16x16x32_bf16(wfr, uf[kt], acc[ct], 0, 0, 0);
            }
        }
        f32x4 acc2 = (f32x4){0.f, 0.f, 0.f, 0.f};
        #pragma unroll
        for (int ct = 0; ct < 4; ++ct) {
            f32x4 g4 = *(const f32x4*)&kk[ct*16 + kg*4];
            f32x4 b4 = *(const f32x4*)&kk[64 + ct*16 + kg*4];
            float v0 = gelu_r(fmaf(inv, acc[ct][0], fmaf(-im, g4[0], b4[0])));
            float v1 = gelu_r(fmaf(inv, acc[ct][1], fmaf(-im, g4[1], b4[1])));
            float v2 = gelu_r(fmaf(inv, acc[ct][2], fmaf(-im, g4[2], b4[2])));
            float v3 = gelu_r(fmaf(inv, acc[ct][3], fmaf(-im, g4[3], b4[3])));
            fp16x2 lo = __builtin_amdgcn_cvt_pkrtz(v0, v1);
            fp16x2 hi = __builtin_amdgcn_cvt_pkrtz(v2, v3);
            f16x4 vgf;
            vgf[0] = (_Float16)lo[0]; vgf[1] = (_Float16)lo[1];
            vgf[2] = (_Float16)hi[0]; vgf[3] = (_Float16)hi[1];
            acc2 = __builtin_amdgcn_mfma_f32_16x16x16f16(w3f[ct], vgf, acc2, 0, 0, 0);
        }
        if (kg == 0) {
            float* op = out + t*3072 + (tile*16 + cLo)*3;
            op[0] = acc2[0] + b30;
            op[1] = acc2[1] + b31;
            op[2] = acc2[2] + b32v;
        }
    };

    f32x4 bufA[4], bufB[4];
    LOADTILE(bufA, 0);
    #pragma unroll 1
    for (int k = 0; k < 16; k += 2) {
        LOADTILE(bufB, k + 1);
        BODY(bufA, qd*16 + k);
        if (k + 2 < 16) LOADTILE(bufA, k + 2);
        BODY(bufB, qd*16 + k + 1);
    }
}

extern "C" void kernel_launch(void* const* d_in, const int* in_sizes, int n_in,
                              void* d_out, int out_size, void* d_ws, size_t ws_size,
                              hipStream_t stream) {
    const float* H         = (const float*)d_in[0];
    const float* qpts      = (const float*)d_in[1];
    const float* qe_W1     = (const float*)d_in[2];
    const float* qe_b1     = (const float*)d_in[3];
    const float* qe_W2     = (const float*)d_in[4];
    const float* qe_b2     = (const float*)d_in[5];
    const float* attn_in_w = (const float*)d_in[6];
    const float* attn_out_w= (const float*)d_in[7];
    const float* ln1_g     = (const float*)d_in[8];
    const float* ln1_b     = (const float*)d_in[9];
    const float* ffn_W1    = (const float*)d_in[10];
    const float* ffn_b1    = (const float*)d_in[11];
    const float* ffn_W2    = (const float*)d_in[12];
    const float* ffn_b2    = (const float*)d_in[13];
    const float* ln2_g     = (const float*)d_in[14];
    const float* ln2_b     = (const float*)d_in[15];
    const float* pm_W1     = (const float*)d_in[16];
    const float* pm_b1     = (const float*)d_in[17];
    const float* pm_ln_g   = (const float*)d_in[18];
    const float* pm_ln_b   = (const float*)d_in[19];
    const float* pm_W2     = (const float*)d_in[20];
    const float* pm_b2     = (const float*)d_in[21];
    const float* pm_W3     = (const float*)d_in[22];
    const float* pm_b3     = (const float*)d_in[23];

    float* ws = (float*)d_ws;
    float* z   = ws;             // 131072
    float* q   = ws + 131072;    // 131072 (q1, then q2)
    float* kb1 = ws + 262144;    // 65536
    float* vb1 = ws + 327680;    // 65536
    float* kb2 = ws + 393216;    // 65536
    float* vb2 = ws + 458752;    // 65536
    float* aH  = ws + 524288;    // 65536
    float* ps  = ws + 720896;    // 65536 (NCH=8)
    float* pa  = ws + 851968;    // 1048576
    __bf16* w2g = (__bf16*)(ws + 2949120);   // 4096 bf16
    float* kgv = ws + 2951168;   // 64
    float* kbv = ws + 2951232;   // 64
    float* out = (float*)d_out;

    pre_kernel<<<512 + 1280 + 1, 256, 0, stream>>>(
        qpts, qe_W1, qe_b1, qe_W2, qe_b2, attn_in_w, pm_W1, H,
        pm_W2, pm_ln_g, pm_ln_b, pm_b2,
        z, q, kb1, vb1, kb2, vb2, aH, w2g, kgv, kbv);
    // layer 0
    attn_part_kernel<<<1024, 256, 0, stream>>>(q, kb1, vb1, ps, pa);
    head_kernel<<<T_/4, 256, 0, stream>>>(ps, pa, attn_out_w, ln1_g, ln1_b,
                                          ffn_W1, ffn_b1, ffn_W2, ffn_b2, ln2_g, ln2_b,
                                          attn_in_w + 192*64, 64, z, q);
    // layer 1 attention
    attn_part_kernel<<<1024, 256, 0, stream>>>(q, kb2, vb2, ps, pa);
    // layer 1 head fused into pair prologue
    pair_kernel<<<2048, 256, 0, stream>>>(
        ps, pa, attn_out_w + 64*64, ln1_g + 64, ln1_b + 64,
        ffn_W1 + 256*64, ffn_b1 + 256, ffn_W2 + 64*256, ffn_b2 + 64,
        ln2_g + 64, ln2_b + 64, pm_W1, z, pm_b1,
        aH, w2g, kgv, kbv, pm_W3, pm_b3, out);
}